// Round 1
// baseline (219.361 us; speedup 1.0000x reference)
//
#include <hip/hip_runtime.h>
#include <math.h>

// Problem constants (from reference setup_inputs)
#define BN   4
#define CN   256
#define HN   128
#define WN   128
#define COMP 64
#define KK   25      // K*K
#define HO   64
#define WO   64

// Workspace layout (floats):
//   w2c  [256][225]   composed conv weights, w2c[c*225 + m*9 + t]
//   tb   [225] (+pad) per-tap b1 contribution: tb[m*9+t] = sum_k w2[m,k,t]*b1[k]
//   mask [4][25][64][64] softmaxed mask
// Total = 57856 + 409600 = 467456 floats = 1.87 MB  (well under ws_size)
#define W2C_ELEMS (256 * 225)
#define TB_OFF    W2C_ELEMS
#define MASK_OFF  (W2C_ELEMS + 256)

// ---------------------------------------------------------------------------
// Kernel A: compose w2c = w2 (25,64,3,3) contracted with w1 (64,256) over k,
// plus per-tap bias tb. One block per (m,t), one thread per c.
// ---------------------------------------------------------------------------
__global__ __launch_bounds__(256) void compose_w(
    const float* __restrict__ w1, const float* __restrict__ b1,
    const float* __restrict__ w2, float* __restrict__ ws) {
  int mt = blockIdx.x;             // 0..224  (m*9 + t)
  int c  = threadIdx.x;            // 0..255
  float acc = 0.f;
#pragma unroll 8
  for (int k = 0; k < COMP; ++k)
    acc += w2[(size_t)(mt / 9 * COMP + k) * 9 + (mt % 9)] * w1[k * CN + c];
  ws[c * 225 + mt] = acc;
  if (c == 0) {
    float tbv = 0.f;
    for (int k = 0; k < COMP; ++k)
      tbv += w2[(size_t)(mt / 9 * COMP + k) * 9 + (mt % 9)] * b1[k];
    ws[TB_OFF + mt] = tbv;
  }
}

// ---------------------------------------------------------------------------
// Kernel B: fused (composed conv3x3 stride2) + softmax over 25.
// Grid: (HO, BN). Block: 512 threads = 8 waves.
// Wave w owns channels [w*32, w*32+32), lane = wo (0..63).
// w2c rows are read as wave-uniform scalar loads (contiguous 225 floats).
// ---------------------------------------------------------------------------
__global__ __launch_bounds__(512) void mask_kernel(
    const float* __restrict__ x, const float* __restrict__ b2,
    const float* __restrict__ ws, float* __restrict__ mask) {
  const int ho  = blockIdx.x;
  const int b   = blockIdx.y;
  const int tid = threadIdx.x;
  const int wo  = tid & 63;
  const int wv  = tid >> 6;                       // 0..7
  // force wave-uniform channel base into an SGPR so w2c loads scalarize
  const int c_base = __builtin_amdgcn_readfirstlane(wv * 32);

  const float* __restrict__ w2c = ws;
  const float* __restrict__ tb  = ws + TB_OFF;

  // 3x3 tap addresses (fixed across channels): clamped offset + validity mult
  int   off[9];
  float vld[9];
#pragma unroll
  for (int dr = 0; dr < 3; ++dr) {
    int r = 2 * ho - 1 + dr;
    int rc = min(max(r, 0), HN - 1);
#pragma unroll
    for (int dc = 0; dc < 3; ++dc) {
      int q  = 2 * wo - 1 + dc;
      int qc = min(max(q, 0), WN - 1);
      bool ok = (r >= 0) & (r < HN) & (q >= 0) & (q < WN);
      off[dr * 3 + dc] = rc * WN + qc;
      vld[dr * 3 + dc] = ok ? 1.f : 0.f;
    }
  }

  float acc[KK];
#pragma unroll
  for (int m = 0; m < KK; ++m) acc[m] = 0.f;

  // prefetch channel 0
  const float* xc = x + ((size_t)(b * CN + c_base)) * HN * WN;
  float xv[9];
#pragma unroll
  for (int t = 0; t < 9; ++t) xv[t] = xc[off[t]] * vld[t];

  for (int ci = 0; ci < 32; ++ci) {
    float xn[9];
    if (ci + 1 < 32) {
      const float* xcn = x + ((size_t)(b * CN + c_base + ci + 1)) * HN * WN;
#pragma unroll
      for (int t = 0; t < 9; ++t) xn[t] = xcn[off[t]] * vld[t];
    }
    const float* __restrict__ wrow = w2c + (size_t)(c_base + ci) * 225;
#pragma unroll
    for (int m = 0; m < KK; ++m) {
      float a = acc[m];
#pragma unroll
      for (int t = 0; t < 9; ++t) a += wrow[m * 9 + t] * xv[t];
      acc[m] = a;
    }
#pragma unroll
    for (int t = 0; t < 9; ++t) xv[t] = xn[t];
  }

  // Two-phase LDS reduction over the 8 waves: [4][25][64]
  __shared__ float lds[4 * KK * 64];
  const int w4 = wv & 3;
  if (wv < 4) {
#pragma unroll
    for (int m = 0; m < KK; ++m) lds[(w4 * KK + m) * 64 + wo] = acc[m];
  }
  __syncthreads();
  if (wv >= 4) {
#pragma unroll
    for (int m = 0; m < KK; ++m) lds[(w4 * KK + m) * 64 + wo] += acc[m];
  }
  __syncthreads();

  if (tid < 64) {
    // wo == tid here; off[]/vld[] of this thread are valid for this wo
    float logit[KK];
    float mx = -1e30f;
#pragma unroll
    for (int m = 0; m < KK; ++m) {
      float l = b2[m];
#pragma unroll
      for (int t = 0; t < 9; ++t) l += vld[t] * tb[m * 9 + t];
      l += lds[(0 * KK + m) * 64 + wo] + lds[(1 * KK + m) * 64 + wo] +
           lds[(2 * KK + m) * 64 + wo] + lds[(3 * KK + m) * 64 + wo];
      logit[m] = l;
      mx = fmaxf(mx, l);
    }
    float s = 0.f;
#pragma unroll
    for (int m = 0; m < KK; ++m) {
      float e = __expf(logit[m] - mx);
      logit[m] = e;
      s += e;
    }
    float inv = 1.f / s;
    const size_t mb = (size_t)b * (KK * HO * WO) + (size_t)ho * WO + wo;
#pragma unroll
    for (int m = 0; m < KK; ++m)
      mask[mb + (size_t)m * (HO * WO)] = logit[m] * inv;
  }
}

// ---------------------------------------------------------------------------
// Kernel C: CARAFE gather. Grid (HO, CN/4, BN), block 256 = 4 channels x 64 wo.
// Mask row staged in LDS; out[b,c,ho,wo] = sum_ij x[b,c,2ho+i-2,2wo+j-2]*m[ij]
// ---------------------------------------------------------------------------
__global__ __launch_bounds__(256) void carafe_kernel(
    const float* __restrict__ x, const float* __restrict__ mask,
    float* __restrict__ out) {
  const int ho = blockIdx.x;
  const int c4 = blockIdx.y;
  const int b  = blockIdx.z;
  const int tid = threadIdx.x;
  const int wo = tid & 63;
  const int cg = tid >> 6;
  const int c  = c4 * 4 + cg;

  __shared__ float sm[KK * 64];
  const size_t mb = (size_t)b * (KK * HO * WO) + (size_t)ho * WO;
  for (int idx = tid; idx < KK * 64; idx += 256) {
    int m = idx >> 6, w = idx & 63;
    sm[idx] = mask[mb + (size_t)m * (HO * WO) + w];
  }
  __syncthreads();

  const float* __restrict__ xc = x + ((size_t)(b * CN + c)) * HN * WN;
  float acc = 0.f;
#pragma unroll
  for (int i = 0; i < 5; ++i) {
    int r = 2 * ho + i - 2;
    if (r < 0 || r >= HN) continue;           // block-uniform branch
    const float* __restrict__ xr = xc + (size_t)r * WN;
#pragma unroll
    for (int j = 0; j < 5; ++j) {
      int q = 2 * wo + j - 2;
      float xvv = (q >= 0 && q < WN) ? xr[q] : 0.f;
      acc += xvv * sm[(i * 5 + j) * 64 + wo];
    }
  }
  out[(((size_t)(b * CN + c)) * HO + ho) * WO + wo] = acc;
}

// ---------------------------------------------------------------------------
extern "C" void kernel_launch(void* const* d_in, const int* in_sizes, int n_in,
                              void* d_out, int out_size, void* d_ws, size_t ws_size,
                              hipStream_t stream) {
  const float* x  = (const float*)d_in[0];
  const float* w1 = (const float*)d_in[1];
  const float* b1 = (const float*)d_in[2];
  const float* w2 = (const float*)d_in[3];
  const float* b2 = (const float*)d_in[4];
  float* out  = (float*)d_out;
  float* ws   = (float*)d_ws;
  float* mask = ws + MASK_OFF;

  hipLaunchKernelGGL(compose_w, dim3(225), dim3(256), 0, stream, w1, b1, w2, ws);
  hipLaunchKernelGGL(mask_kernel, dim3(HO, BN), dim3(512), 0, stream, x, b2, ws, mask);
  hipLaunchKernelGGL(carafe_kernel, dim3(HO, CN / 4, BN), dim3(256), 0, stream,
                     x, mask, out);
}

// Round 2
// 194.301 us; speedup vs baseline: 1.1290x; 1.1290x over previous
//
#include <hip/hip_runtime.h>
#include <math.h>

// Problem constants
#define BN   4
#define CN   256
#define HN   128
#define WN   128
#define COMP 64
#define KK   25      // K*K
#define HO   64
#define WO   64
#define NW   16      // waves per fused block
#define CPW  (CN / NW)  // 16 channels per wave

// Workspace layout (floats): w2c[256][225], tb[225] (+pad)
#define W2C_ELEMS (256 * 225)
#define TB_OFF    W2C_ELEMS

// ---------------------------------------------------------------------------
// Kernel A: compose w2c[c][m,t] = sum_k w2[m,k,t] * w1[k,c]; tb[m,t] =
// sum_k w2[m,k,t] * b1[k]. One block per (m,t)=mt, one thread per c.
// ---------------------------------------------------------------------------
__global__ __launch_bounds__(256) void compose_w(
    const float* __restrict__ w1, const float* __restrict__ b1,
    const float* __restrict__ w2, float* __restrict__ ws) {
  int mt = blockIdx.x;             // 0..224
  int c  = threadIdx.x;            // 0..255
  float acc = 0.f;
#pragma unroll 8
  for (int k = 0; k < COMP; ++k)
    acc += w2[(size_t)(mt / 9 * COMP + k) * 9 + (mt % 9)] * w1[k * CN + c];
  ws[c * 225 + mt] = acc;
  if (c == 0) {
    float tbv = 0.f;
    for (int k = 0; k < COMP; ++k)
      tbv += w2[(size_t)(mt / 9 * COMP + k) * 9 + (mt % 9)] * b1[k];
    ws[TB_OFF + mt] = tbv;
  }
}

// ---------------------------------------------------------------------------
// Fused kernel: composed conv3x3(stride2) -> softmax(25) -> CARAFE gather.
// Grid (HO, BN) = 256 blocks, 1024 threads = 16 waves.
// Wave wv owns channels [wv*16, wv*16+16); lane = wo (0..63).
// All x loads are coalesced float2 at col 2*wo; odd/neighbor columns come
// from __shfl_up/__shfl_down. w2c rows load as wave-uniform scalar (s_load).
// ---------------------------------------------------------------------------
__global__ __launch_bounds__(1024, 4) void fused_kernel(
    const float* __restrict__ x, const float* __restrict__ b2,
    const float* __restrict__ ws, float* __restrict__ out) {
  const int ho  = blockIdx.x;
  const int b   = blockIdx.y;
  const int tid = threadIdx.x;
  const int wo  = tid & 63;
  const int wv  = tid >> 6;                        // 0..15
  const int c_base = __builtin_amdgcn_readfirstlane(wv * CPW);

  const float* __restrict__ w2c = ws;
  const float* __restrict__ tb  = ws + TB_OFF;

  __shared__ float red[8 * KK * 64];   // 51200 B reduction buffers
  __shared__ float sm[KK * 64];        //  6400 B softmaxed mask row

  const float* __restrict__ xb = x + (size_t)(b * CN) * (HN * WN);
  const int col = 2 * wo;              // float2 load covers cols {2wo, 2wo+1}

  // ---------------- Phase 1: conv (rows 2ho-1 .. 2ho+1) ----------------
  float acc[KK];
#pragma unroll
  for (int m = 0; m < KK; ++m) acc[m] = 0.f;

  float2 buf[2][3];
  auto load_ch = [&](int ci, float2* dst) {
    const float* xc = xb + (size_t)(c_base + ci) * (HN * WN);
    dst[0] = (ho > 0) ? *(const float2*)(xc + (2 * ho - 1) * WN + col)
                      : make_float2(0.f, 0.f);
    dst[1] = *(const float2*)(xc + (2 * ho) * WN + col);
    dst[2] = *(const float2*)(xc + (2 * ho + 1) * WN + col);
  };
  load_ch(0, buf[0]);
  load_ch(1, buf[1]);

  const float wok = (wo > 0) ? 1.f : 0.f;
  for (int ci = 0; ci < CPW; ++ci) {
    float2 r0 = buf[ci & 1][0], r1 = buf[ci & 1][1], r2 = buf[ci & 1][2];
    if (ci + 2 < CPW) load_ch(ci + 2, buf[ci & 1]);

    float xv[9];
    xv[0] = wok * __shfl_up(r0.y, 1, 64); xv[1] = r0.x; xv[2] = r0.y;
    xv[3] = wok * __shfl_up(r1.y, 1, 64); xv[4] = r1.x; xv[5] = r1.y;
    xv[6] = wok * __shfl_up(r2.y, 1, 64); xv[7] = r2.x; xv[8] = r2.y;

    const float* __restrict__ wrow = w2c + (size_t)(c_base + ci) * 225;
#pragma unroll
    for (int m = 0; m < KK; ++m) {
      float a = acc[m];
#pragma unroll
      for (int t = 0; t < 9; ++t) a += wrow[m * 9 + t] * xv[t];
      acc[m] = a;
    }
  }

  // ---------------- Reduction across 16 waves ----------------
  if (wv >= 8) {
#pragma unroll
    for (int m = 0; m < KK; ++m) red[((wv - 8) * KK + m) * 64 + wo] = acc[m];
  }
  __syncthreads();
  if (wv < 8) {
#pragma unroll
    for (int m = 0; m < KK; ++m) red[(wv * KK + m) * 64 + wo] += acc[m];
  }
  __syncthreads();
  if (wv < 4) {
#pragma unroll
    for (int m = 0; m < KK; ++m)
      red[(wv * KK + m) * 64 + wo] += red[((wv + 4) * KK + m) * 64 + wo];
  }
  __syncthreads();
  if (wv < 2) {
#pragma unroll
    for (int m = 0; m < KK; ++m)
      red[(wv * KK + m) * 64 + wo] += red[((wv + 2) * KK + m) * 64 + wo];
  }
  __syncthreads();

  // ---------------- Softmax (one wave) ----------------
  if (tid < 64) {
    const float vr0 = (ho > 0) ? 1.f : 0.f;   // row 2ho-1 validity
    const float vq0 = (wo > 0) ? 1.f : 0.f;   // col 2wo-1 validity
    float logit[KK];
    float mx = -1e30f;
#pragma unroll
    for (int m = 0; m < KK; ++m) {
      const float* t9 = tb + m * 9;
      float l = b2[m]
              + vr0 * (vq0 * t9[0] + t9[1] + t9[2])
              +       (vq0 * t9[3] + t9[4] + t9[5])
              +       (vq0 * t9[6] + t9[7] + t9[8]);
      l += red[(0 * KK + m) * 64 + wo] + red[(1 * KK + m) * 64 + wo];
      logit[m] = l;
      mx = fmaxf(mx, l);
    }
    float s = 0.f;
#pragma unroll
    for (int m = 0; m < KK; ++m) {
      float e = __expf(logit[m] - mx);
      logit[m] = e;
      s += e;
    }
    float inv = 1.f / s;
#pragma unroll
    for (int m = 0; m < KK; ++m) sm[m * 64 + wo] = logit[m] * inv;
  }
  __syncthreads();

  // ---------------- Phase 2: CARAFE gather (rows 2ho-2 .. 2ho+2) ----------
  float smr[KK];
#pragma unroll
  for (int m = 0; m < KK; ++m) smr[m] = sm[m * 64 + wo];

  float2 g[2][5];
  auto load_g = [&](int ci, float2* dst) {
    const float* xc = xb + (size_t)(c_base + ci) * (HN * WN);
#pragma unroll
    for (int i = 0; i < 5; ++i) {
      int r = 2 * ho - 2 + i;
      dst[i] = (r >= 0 && r < HN) ? *(const float2*)(xc + r * WN + col)
                                  : make_float2(0.f, 0.f);
    }
  };
  load_g(0, g[0]);
  load_g(1, g[1]);

  const float w63 = (wo < 63) ? 1.f : 0.f;
  for (int ci = 0; ci < CPW; ++ci) {
    float2 v[5];
#pragma unroll
    for (int i = 0; i < 5; ++i) v[i] = g[ci & 1][i];
    if (ci + 2 < CPW) load_g(ci + 2, g[ci & 1]);

    float acc2 = 0.f;
#pragma unroll
    for (int i = 0; i < 5; ++i) {
      float lx = wok * __shfl_up(v[i].x, 1, 64);    // col 2wo-2
      float ly = wok * __shfl_up(v[i].y, 1, 64);    // col 2wo-1
      float rx = w63 * __shfl_down(v[i].x, 1, 64);  // col 2wo+2
      acc2 += lx * smr[i * 5 + 0] + ly * smr[i * 5 + 1]
            + v[i].x * smr[i * 5 + 2] + v[i].y * smr[i * 5 + 3]
            + rx * smr[i * 5 + 4];
    }
    out[(((size_t)(b * CN + c_base + ci)) * HO + ho) * WO + wo] = acc2;
  }
}

// ---------------------------------------------------------------------------
extern "C" void kernel_launch(void* const* d_in, const int* in_sizes, int n_in,
                              void* d_out, int out_size, void* d_ws, size_t ws_size,
                              hipStream_t stream) {
  const float* x  = (const float*)d_in[0];
  const float* w1 = (const float*)d_in[1];
  const float* b1 = (const float*)d_in[2];
  const float* w2 = (const float*)d_in[3];
  const float* b2 = (const float*)d_in[4];
  float* out = (float*)d_out;
  float* ws  = (float*)d_ws;

  hipLaunchKernelGGL(compose_w, dim3(225), dim3(256), 0, stream, w1, b1, w2, ws);
  hipLaunchKernelGGL(fused_kernel, dim3(HO, BN), dim3(1024), 0, stream,
                     x, b2, ws, out);
}